// Round 12
// baseline (1129.213 us; speedup 1.0000x reference)
//
#include <hip/hip_runtime.h>

#define TT 128
#define BB 32
#define II 128
#define HH 320
#define OO 32
#define GG 8
#define RW 20      // rows per wave (8 waves x 20 = 160 rows per block)
#define HB 160     // rows per block
#define HPAD 129   // s_hist row pitch

static __device__ __forceinline__ float fexp2(float x) { return __builtin_amdgcn_exp2f(x); }
static __device__ __forceinline__ float frcp(float x)  { return __builtin_amdgcn_rcpf(x); }

// tanh for x >= 0: 1 - 2/(e^{2x}+1)
static __device__ __forceinline__ float tanh_pos(float x) {
    float e = fexp2(x * 2.8853900817779268f);
    return 1.0f - 2.0f * frcp(e + 1.0f);
}

// ---- DPP wave-64 sum reduce (VALU pipe) ----
template<int CTRL>
static __device__ __forceinline__ float dpp_add(float v) {
    int t = __builtin_amdgcn_update_dpp(0, __builtin_bit_cast(int, v),
                                        CTRL, 0xf, 0xf, true);
    return v + __builtin_bit_cast(float, t);
}
static __device__ __forceinline__ float bcast63(float v) {
    return __builtin_bit_cast(float,
        __builtin_amdgcn_readlane(__builtin_bit_cast(int, v), 63));
}
static __device__ __forceinline__ float wave_sum(float v) {
    v = dpp_add<0x111>(v);   // row_shr:1
    v = dpp_add<0x112>(v);   // row_shr:2
    v = dpp_add<0x114>(v);   // row_shr:4
    v = dpp_add<0x118>(v);   // row_shr:8
    v = dpp_add<0x142>(v);   // row_bcast:15
    v = dpp_add<0x143>(v);   // row_bcast:31
    return bcast63(v);
}

// 2 blocks per batch (min possible: 560KB plastic state/batch > one CU's 512KB
// VGPR file). One remote producer per consumer -> no 7-way straggler max.
__global__ __launch_bounds__(512, 1)
void leaky_rnn_kernel(const float* __restrict__ x, const float* __restrict__ Rs,
                      const float* __restrict__ Wx2h, const float* __restrict__ Wh2h,
                      const float* __restrict__ bh2h, const float* __restrict__ Wh2o,
                      const float* __restrict__ bh2o, const float* __restrict__ Wattn,
                      const float* __restrict__ battn, const float* __restrict__ cplas,
                      float* __restrict__ out, float* __restrict__ hs,
                      unsigned* __restrict__ ctr)
{
    const int tid  = threadIdx.x;
    const int bid  = blockIdx.x;       // 64 blocks
    const int b    = bid >> 1;         // batch
    const int sub  = bid & 1;          // half: rows [sub*160, sub*160+160)
    const int w    = tid >> 6;         // wave 0..7
    const int lane = tid & 63;
    const int h0   = sub * HB;
    const int hw   = h0 + w * RW;      // this wave's first row

    __shared__ float s_ea[GG * HH];      // masked relu(W_attn)
    __shared__ float s_out[2][HH];       // double-buffered prev-output (t parity)
    __shared__ float s_logit[GG];
    __shared__ float s_hist[HB * HPAD];  // own 160 rows x 128 t (true values);
                                         // in-loop WRITTEN only, READ in final phase.
    __shared__ float s_hs[16 * HH];      // readout staging (4 passes of 16 t)

    // ---- one-time init ----
    for (int idx = tid; idx < GG * HH; idx += 512) {
        int h = idx % HH;
        float m = (h < 256) ? 1.f : (h == 256 ? -1.f : 0.f);  // mask_a (zc=63!)
        s_ea[idx] = fmaxf(Wattn[idx], 0.f) * m;
    }
    if (tid < HH) { s_out[0][tid] = 0.f; s_out[1][tid] = 0.f; }  // output0 = relu(0)

    // plastic weights in registers: 20 rows/wave, lane owns cols {lane+64c}
    float wx[RW][2], wh[RW][5], st[RW], bh[RW];
#pragma unroll
    for (int r = 0; r < RW; ++r) {
        int h = hw + r;
        bh[r] = bh2h[h];
        st[r] = 0.f;
#pragma unroll
        for (int c = 0; c < 2; ++c)
            wx[r][c] = fmaxf(Wx2h[h * II + lane + 64 * c], 0.f);   // relu(W_x2h)
#pragma unroll
        for (int c = 0; c < 5; ++c) {
            int j = lane + 64 * c;
            float v = fmaxf(Wh2h[h * HH + j], 0.f);
            v = (c == 4) ? -v : v;            // sign_h: j>=256 -> -1
            wh[r][c] = (j == h) ? 0.f : v;    // zero diagonal (1-eye)
        }
    }
    float batt = battn[w];  // wave w handles attn group g = w
    float c0 = fabsf(cplas[0]), c1 = fabsf(cplas[1]), c2 = fabsf(cplas[2]);
    float c3 = fabsf(cplas[3]), c4 = fabsf(cplas[4]), c5 = fabsf(cplas[5]);

    const float AX  = (float)(0.02 / 0.1);   // 0.2
    const float AW  = (float)(0.02 / 0.2);   // 0.1
    const float OMX = 1.f - AX;
    const float OMW = 1.f - AW;
    const float L2E = 1.4426950408889634f;

    __syncthreads();

    // prefetch x (both halves) and Rs for t=0
    float xv0n = x[b * II + lane];
    float xv1n = x[b * II + lane + 64];
    float Rvn  = Rs[b];

#pragma unroll 1
    for (int t = 0; t < TT; ++t) {
        const float* so_cur = s_out[t & 1];
        float*       so_nxt = s_out[(t + 1) & 1];
        float xv0 = xv0n, xv1 = xv1n;
        float A   = AW * Rvn;

        // ---- attention logits: g = w, reduce over H (DPP) ----
        float lp = 0.f;
#pragma unroll
        for (int k = 0; k < 5; ++k) {
            int hh2 = lane + 64 * k;
            lp = fmaf(s_ea[w * HH + hh2], so_cur[hh2], lp);
        }
        float lt = wave_sum(lp);
        if (lane == 0) s_logit[w] = lt + batt;
        __syncthreads();                                   // B1: s_logit visible

        // ---- redundant per-thread softmax (R2-proven op order) ----
        float lg[8];
#pragma unroll
        for (int g = 0; g < 8; ++g) lg[g] = s_logit[g];
        float mx = lg[0];
#pragma unroll
        for (int g = 1; g < 8; ++g) mx = fmaxf(mx, lg[g]);
        float se = 0.f, eg[8];
#pragma unroll
        for (int g = 0; g < 8; ++g) { eg[g] = fexp2((lg[g] - mx) * L2E); se += eg[g]; }
        float rinv = frcp(se);
        float xmc0 = xv0 * eg[lane >> 4] * 8.f * rinv;
        float xmc1 = xv1 * eg[(lane >> 4) + 4] * 8.f * rinv;

        float oc[5];
#pragma unroll
        for (int c = 0; c < 5; ++c) oc[c] = so_cur[lane + 64 * c];

        // ---- 20 row-dot partials, 20-way ILP DPP reduce ----
        float p[RW];
#pragma unroll
        for (int r = 0; r < RW; ++r) {
            int h = hw + r;
            float pp = fmaxf(wx[r][0], 0.f) * xmc0;
            pp = fmaf(fmaxf(wx[r][1], 0.f), xmc1, pp);
#pragma unroll
            for (int c = 0; c < 5; ++c) {
                float wv = fmaxf(wh[r][c], 0.f);
                float so = (c == 4) ? -oc[4] : oc[c];        // sign_h fold
                float term = wv * so;
                term = ((lane + 64 * c) == h) ? 0.f : term;  // exclude diagonal
                pp += term;
            }
            p[r] = pp;
        }
#define DPP_LALL(CTRL) { \
        _Pragma("unroll") \
        for (int r = 0; r < RW; ++r) p[r] = dpp_add<CTRL>(p[r]); }
        DPP_LALL(0x111) DPP_LALL(0x112) DPP_LALL(0x114)
        DPP_LALL(0x118) DPP_LALL(0x142) DPP_LALL(0x143)
#undef DPP_LALL

        // ---- state update + tanh + fold publish-select + weight update
        //      per-row (keeps no[] out of the register file) ----
        float pub = 0.f;
        float Ac0 = A * c0, Ac1 = A * c1, Ac2 = A * c2;
        float Ac3 = A * c3, Ac4 = A * c4, Ac5 = A * c5;
#pragma unroll
        for (int r = 0; r < RW; ++r) {
            float total = bcast63(p[r]) + bh[r];
            st[r] = fmaf(st[r], OMX, total * AX);
            float no_r = tanh_pos(fmaxf(st[r], 0.f));
            pub = (lane == r) ? no_r : pub;
            if (t < TT - 1) {
                float u  = fmaf(Ac2, no_r, Ac0);
                float v  = Ac1 * no_r;
                float pq = fmaf(Ac5, no_r, Ac3);
                float qq = Ac4 * no_r;
                wx[r][0] = fmaf(wx[r][0], OMW, fmaf(u, xmc0, v));
                wx[r][1] = fmaf(wx[r][1], OMW, fmaf(u, xmc1, v));
#pragma unroll
                for (int c = 0; c < 5; ++c)
                    wh[r][c] = fmaf(wh[r][c], OMW, fmaf(pq, oc[c], qq));
            }
        }

        // ---- batched publish: lanes 0..19 store 20 consecutive h.
        //      Biased (+2): poison / memset-0 are < 1. Publisher also
        //      writes so_nxt (LDS own-row fast path, B2-ordered). ----
        if (lane < RW) {
            __hip_atomic_store(&hs[(t * BB + b) * HH + hw + lane], pub + 2.0f,
                               __ATOMIC_RELAXED, __HIP_MEMORY_SCOPE_AGENT);
            s_hist[(w * RW + lane) * HPAD + t] = pub;   // true value, final phase only
            so_nxt[hw + lane] = pub;                    // own-row fast path (B2-ordered)
        }

        // prefetch next x/R while publish stores are in flight
        if (t + 1 < TT) {
            xv0n = x[((t + 1) * BB + b) * II + lane];
            xv1n = x[((t + 1) * BB + b) * II + lane + 64];
            Rvn  = Rs[(t + 1) * BB + b];
        }

        // ---- gather the 160 REMOTE rows (single producer block!) into the
        //      other buffer. Proven agent 4-deep pipelined poll (R7/R8). ----
        if (t < TT - 1 && tid < HH && !(tid >= h0 && tid < h0 + HB)) {
            const float* p2 = &hs[(t * BB + b) * HH + tid];
            float va = __hip_atomic_load(p2, __ATOMIC_RELAXED, __HIP_MEMORY_SCOPE_AGENT);
            float vb = __hip_atomic_load(p2, __ATOMIC_RELAXED, __HIP_MEMORY_SCOPE_AGENT);
            float vc = __hip_atomic_load(p2, __ATOMIC_RELAXED, __HIP_MEMORY_SCOPE_AGENT);
            float vd = __hip_atomic_load(p2, __ATOMIC_RELAXED, __HIP_MEMORY_SCOPE_AGENT);
            int guard = 0;
            while (va < 1.0f && ++guard < 2000000) {   // failsafe: never hang
                va = vb; vb = vc; vc = vd;
                vd = __hip_atomic_load(p2, __ATOMIC_RELAXED, __HIP_MEMORY_SCOPE_AGENT);
            }
            so_nxt[tid] = va - 2.0f;
        }
        __syncthreads();                                   // B2: so_nxt sealed
    }

    // ======== final phase ========
    // Barrier A between the 2 sibling blocks: all hs published.
    if (tid == 0) {
        __hip_atomic_fetch_add(&ctr[b * 32], 1u, __ATOMIC_RELAXED, __HIP_MEMORY_SCOPE_AGENT);
        int guard = 0;
        while (__hip_atomic_load(&ctr[b * 32], __ATOMIC_RELAXED, __HIP_MEMORY_SCOPE_AGENT) < 2u) {
            if (++guard > 2000000) break;
            __builtin_amdgcn_s_sleep(1);
        }
    }
    __syncthreads();

    // readout: this block handles t in [sub*64, sub*64+64), 4 passes of 16 t
#pragma unroll 1
    for (int pass = 0; pass < 4; ++pass) {
        for (int idx = tid; idx < 16 * HH; idx += 512) {
            int tl = idx / HH, h = idx % HH;
            int t_g = sub * 64 + pass * 16 + tl;
            s_hs[idx] = __hip_atomic_load(&hs[(t_g * BB + b) * HH + h],
                                          __ATOMIC_RELAXED, __HIP_MEMORY_SCOPE_AGENT) - 2.0f;
        }
        __syncthreads();
        {
            int t_loc = tid >> 5;          // 0..15
            int o     = tid & 31;
            int t_g   = sub * 64 + pass * 16 + t_loc;
            const float* hp = &s_hs[t_loc * HH];
            float acc = bh2o[o];
#pragma unroll 4
            for (int h = 0; h < 257; ++h) {          // mask_o zero for h>256
                float m = (h == 256) ? -1.f : 1.f;   // h==256: sign -1, exist 1
                acc = fmaf(fmaxf(Wh2o[o * HH + h], 0.f) * m, hp[h], acc);
            }
            float sg = frcp(1.f + fexp2(-acc * L2E));
            out[(t_g * BB + b) * OO + o] = sg;
        }
        __syncthreads();   // s_hs reads done before next pass restages
    }

    // Barrier B: both siblings finished READING biased hs -> safe to rewrite
    if (tid == 0) {
        __hip_atomic_fetch_add(&ctr[b * 32], 1u, __ATOMIC_RELAXED, __HIP_MEMORY_SCOPE_AGENT);
        int guard = 0;
        while (__hip_atomic_load(&ctr[b * 32], __ATOMIC_RELAXED, __HIP_MEMORY_SCOPE_AGENT) < 4u) {
            if (++guard > 2000000) break;
            __builtin_amdgcn_s_sleep(1);
        }
    }
    __syncthreads();

    // rewrite own 160 rows of hs with TRUE values (word-granular agent stores)
    for (int idx = tid; idx < HB * TT; idx += 512) {
        int row = idx >> 7;            // idx / 128
        int t   = idx & 127;
        __hip_atomic_store(&hs[(t * BB + b) * HH + h0 + row], s_hist[row * HPAD + t],
                           __ATOMIC_RELAXED, __HIP_MEMORY_SCOPE_AGENT);
    }
}

extern "C" void kernel_launch(void* const* d_in, const int* in_sizes, int n_in,
                              void* d_out, int out_size, void* d_ws, size_t ws_size,
                              hipStream_t stream) {
    const float* x     = (const float*)d_in[0];
    const float* Rs    = (const float*)d_in[1];
    const float* Wx2h  = (const float*)d_in[2];
    const float* Wh2h  = (const float*)d_in[3];
    const float* bh2h  = (const float*)d_in[4];
    const float* Wh2o  = (const float*)d_in[5];
    const float* bh2o  = (const float*)d_in[6];
    const float* Wattn = (const float*)d_in[7];
    const float* battn = (const float*)d_in[8];
    const float* cplas = (const float*)d_in[9];
    float* out = (float*)d_out;
    float* hs  = out + TT * BB * OO;
    unsigned* ctr = (unsigned*)d_ws;   // 32 counters, 128B apart

    hipMemsetAsync(d_ws, 0, 32 * 32 * sizeof(unsigned), stream);
    hipLaunchKernelGGL(leaky_rnn_kernel, dim3(64), dim3(512), 0, stream,
                       x, Rs, Wx2h, Wh2h, bh2h, Wh2o, bh2o, Wattn, battn, cplas,
                       out, hs, ctr);
}

// Round 13
// 457.973 us; speedup vs baseline: 2.4657x; 2.4657x over previous
//
#include <hip/hip_runtime.h>

#define TT 128
#define BB 32
#define II 128
#define HH 320
#define OO 32
#define GG 8
#define HPAD 129   // s_hist row pitch (pad: rows are read down-column in final rewrite)

static __device__ __forceinline__ float fexp2(float x) { return __builtin_amdgcn_exp2f(x); }
static __device__ __forceinline__ float frcp(float x)  { return __builtin_amdgcn_rcpf(x); }

// tanh for x >= 0: 1 - 2/(e^{2x}+1)
static __device__ __forceinline__ float tanh_pos(float x) {
    float e = fexp2(x * 2.8853900817779268f);
    return 1.0f - 2.0f * frcp(e + 1.0f);
}

// ---- DPP wave-64 sum reduce (VALU pipe) ----
template<int CTRL>
static __device__ __forceinline__ float dpp_add(float v) {
    int t = __builtin_amdgcn_update_dpp(0, __builtin_bit_cast(int, v),
                                        CTRL, 0xf, 0xf, true);
    return v + __builtin_bit_cast(float, t);
}
static __device__ __forceinline__ float bcast63(float v) {
    return __builtin_bit_cast(float,
        __builtin_amdgcn_readlane(__builtin_bit_cast(int, v), 63));
}
static __device__ __forceinline__ float wave_sum(float v) {
    v = dpp_add<0x111>(v);   // row_shr:1
    v = dpp_add<0x112>(v);   // row_shr:2
    v = dpp_add<0x114>(v);   // row_shr:4
    v = dpp_add<0x118>(v);   // row_shr:8
    v = dpp_add<0x142>(v);   // row_bcast:15
    v = dpp_add<0x143>(v);   // row_bcast:31
    return bcast63(v);
}

__global__ __launch_bounds__(512, 2)
void leaky_rnn_kernel(const float* __restrict__ x, const float* __restrict__ Rs,
                      const float* __restrict__ Wx2h, const float* __restrict__ Wh2h,
                      const float* __restrict__ bh2h, const float* __restrict__ Wh2o,
                      const float* __restrict__ bh2o, const float* __restrict__ Wattn,
                      const float* __restrict__ battn, const float* __restrict__ cplas,
                      float* __restrict__ out, float* __restrict__ hs,
                      unsigned* __restrict__ ctr)
{
    const int tid  = threadIdx.x;
    const int bid  = blockIdx.x;
    const int b    = bid >> 3;     // batch  (round-0 proven mapping)
    const int sub  = bid & 7;      // 8 blocks per batch, 40 rows each
    const int w    = tid >> 6;     // wave 0..7
    const int lane = tid & 63;
    const int h0   = sub * 40;

    __shared__ float s_ea[GG * HH];      // masked relu(W_attn)
    __shared__ float s_out[2][HH];       // double-buffered prev-output (t parity)
    __shared__ float s_logit[GG];
    __shared__ float s_pub[40];          // this step's 40 own-row outputs (true vals)
    __shared__ float s_hist[40 * HPAD];  // own 40 rows x 128 t; in-loop WRITTEN only,
                                         // READ only in the final phase after barriers.
    __shared__ float s_hs[16 * HH];      // readout staging

    // ---- one-time init ----
    for (int idx = tid; idx < GG * HH; idx += 512) {
        int h = idx % HH;
        float m = (h < 256) ? 1.f : (h == 256 ? -1.f : 0.f);  // mask_a (zc=63!)
        s_ea[idx] = fmaxf(Wattn[idx], 0.f) * m;
    }
    if (tid < HH) { s_out[0][tid] = 0.f; s_out[1][tid] = 0.f; }  // output0 = relu(0)

    // plastic weights in registers: 5 rows/wave, lane owns cols {lane, lane+64,...}
    float wx[5][2], wh[5][5], st[5], bh[5];
    int hrow[5];
#pragma unroll
    for (int r = 0; r < 5; ++r) {
        int h = h0 + w * 5 + r;
        hrow[r] = h;
        bh[r] = bh2h[h];
        st[r] = 0.f;
#pragma unroll
        for (int c = 0; c < 2; ++c)
            wx[r][c] = fmaxf(Wx2h[h * II + lane + 64 * c], 0.f);   // wx0 = relu(W_x2h)
#pragma unroll
        for (int c = 0; c < 5; ++c) {
            int j = lane + 64 * c;
            float v = fmaxf(Wh2h[h * HH + j], 0.f);
            v = (c == 4) ? -v : v;            // sign_h: j>=256 -> -1
            wh[r][c] = (j == h) ? 0.f : v;    // zero diagonal (1-eye)
        }
    }
    float batt = battn[w];  // wave w handles attn group g = w
    float c0 = fabsf(cplas[0]), c1 = fabsf(cplas[1]), c2 = fabsf(cplas[2]);
    float c3 = fabsf(cplas[3]), c4 = fabsf(cplas[4]), c5 = fabsf(cplas[5]);

    const float AX  = (float)(0.02 / 0.1);   // 0.2
    const float AW  = (float)(0.02 / 0.2);   // 0.1
    const float OMX = 1.f - AX;
    const float OMW = 1.f - AW;
    const float L2E = 1.4426950408889634f;

    __syncthreads();

    // prefetch x (both halves, per-thread regs) and Rs for t=0
    float xv0n = x[b * II + lane];
    float xv1n = x[b * II + lane + 64];
    float Rvn  = Rs[b];

    // remote-row assignment for the poll phase: threads of waves 0..6
    // (tid 0..447) cover the 280 rows outside [h0, h0+40).
    const int prow = (tid < 280) ? ((tid < h0) ? tid : tid + 40) : -1;

#pragma unroll 1
    for (int t = 0; t < TT; ++t) {
        const float* so_cur = s_out[t & 1];
        float*       so_nxt = s_out[(t + 1) & 1];
        float xv0 = xv0n, xv1 = xv1n;
        float A   = AW * Rvn;

        // ---- attention logits: g = w, reduce over H (DPP, VALU pipe) ----
        float lp = 0.f;
#pragma unroll
        for (int k = 0; k < 5; ++k) {
            int hh2 = lane + 64 * k;
            lp = fmaf(s_ea[w * HH + hh2], so_cur[hh2], lp);
        }
        float lt = wave_sum(lp);
        if (lane == 0) s_logit[w] = lt + batt;
        __syncthreads();                                   // B1: s_logit visible

        // ---- redundant per-thread softmax (R2-proven op order) ----
        float lg[8];
#pragma unroll
        for (int g = 0; g < 8; ++g) lg[g] = s_logit[g];
        float mx = lg[0];
#pragma unroll
        for (int g = 1; g < 8; ++g) mx = fmaxf(mx, lg[g]);
        float se = 0.f, eg[8];
#pragma unroll
        for (int g = 0; g < 8; ++g) { eg[g] = fexp2((lg[g] - mx) * L2E); se += eg[g]; }
        float rinv = frcp(se);
        float xmc0 = xv0 * eg[lane >> 4] * 8.f * rinv;
        float xmc1 = xv1 * eg[(lane >> 4) + 4] * 8.f * rinv;

        float oc[5];
#pragma unroll
        for (int c = 0; c < 5; ++c) oc[c] = so_cur[lane + 64 * c];

        // ---- 5 row-dot partials, 5-way ILP DPP reduce ----
        float p[5];
#pragma unroll
        for (int r = 0; r < 5; ++r) {
            int h = hrow[r];
            float pp = fmaxf(wx[r][0], 0.f) * xmc0;
            pp = fmaf(fmaxf(wx[r][1], 0.f), xmc1, pp);
#pragma unroll
            for (int c = 0; c < 5; ++c) {
                float wv = fmaxf(wh[r][c], 0.f);
                float so = (c == 4) ? -oc[4] : oc[c];        // sign_h fold
                float term = wv * so;
                term = ((lane + 64 * c) == h) ? 0.f : term;  // exclude diagonal
                pp += term;
            }
            p[r] = pp;
        }
#define DPP_L5(CTRL) { \
        p[0]=dpp_add<CTRL>(p[0]); p[1]=dpp_add<CTRL>(p[1]); \
        p[2]=dpp_add<CTRL>(p[2]); p[3]=dpp_add<CTRL>(p[3]); \
        p[4]=dpp_add<CTRL>(p[4]); }
        DPP_L5(0x111) DPP_L5(0x112) DPP_L5(0x114)
        DPP_L5(0x118) DPP_L5(0x142) DPP_L5(0x143)
#undef DPP_L5

        float no[5];
#pragma unroll
        for (int r = 0; r < 5; ++r) {
            float total = bcast63(p[r]) + bh[r];
            st[r] = fmaf(st[r], OMX, total * AX);
            no[r] = tanh_pos(fmaxf(st[r], 0.f));
        }

        // ---- LDS-only publish by compute waves: s_pub (for the delegated
        //      global store), so_nxt (own-row fast path), s_hist (final
        //      rewrite). All ordered for readers by Bmid / B2. ----
        {
            float pub = no[0];
            pub = (lane == 1) ? no[1] : pub;
            pub = (lane == 2) ? no[2] : pub;
            pub = (lane == 3) ? no[3] : pub;
            pub = (lane == 4) ? no[4] : pub;
            if (lane < 5) {
                s_pub[w * 5 + lane] = pub;
                s_hist[(w * 5 + lane) * HPAD + t] = pub;
                so_nxt[h0 + w * 5 + lane] = pub;
            }
        }
        __syncthreads();                                   // Bmid: s_pub sealed

        // ---- DELEGATED publish: wave 7 alone issues the agent store for all
        //      40 rows (one coalesced 160B line). Polling waves (0..4, which
        //      contain the 280 poll threads) now have a STORE-FREE vmcnt FIFO:
        //      their poll-load waits no longer drain a ~2000cy LLC store ack. ----
        if (w == 7 && lane < 40) {
            __hip_atomic_store(&hs[(t * BB + b) * HH + h0 + lane], s_pub[lane] + 2.0f,
                               __ATOMIC_RELAXED, __HIP_MEMORY_SCOPE_AGENT);
        }

        // ---- issue poll loads EARLY (oldest in FIFO); check them after the
        //      weight update + prefetch have been issued (latency hides). ----
        float va = 2.5f, vb = 0.f, vc = 0.f, vd = 0.f;
        const float* p2 = nullptr;
        if (t < TT - 1 && prow >= 0) {
            p2 = &hs[(t * BB + b) * HH + prow];
            va = __hip_atomic_load(p2, __ATOMIC_RELAXED, __HIP_MEMORY_SCOPE_AGENT);
            vb = __hip_atomic_load(p2, __ATOMIC_RELAXED, __HIP_MEMORY_SCOPE_AGENT);
            vc = __hip_atomic_load(p2, __ATOMIC_RELAXED, __HIP_MEMORY_SCOPE_AGENT);
            vd = __hip_atomic_load(p2, __ATOMIC_RELAXED, __HIP_MEMORY_SCOPE_AGENT);
        }

        // ---- plastic weight update (regs only; overlaps poll-load latency) ----
        if (t < TT - 1) {
            float Ac0 = A * c0, Ac1 = A * c1, Ac2 = A * c2;
            float Ac3 = A * c3, Ac4 = A * c4, Ac5 = A * c5;
#pragma unroll
            for (int r = 0; r < 5; ++r) {
                float u  = fmaf(Ac2, no[r], Ac0);
                float v  = Ac1 * no[r];
                float pp = fmaf(Ac5, no[r], Ac3);
                float qq = Ac4 * no[r];
                wx[r][0] = fmaf(wx[r][0], OMW, fmaf(u, xmc0, v));
                wx[r][1] = fmaf(wx[r][1], OMW, fmaf(u, xmc1, v));
#pragma unroll
                for (int c = 0; c < 5; ++c)
                    wh[r][c] = fmaf(wh[r][c], OMW, fmaf(pp, oc[c], qq));
            }
        }

        // prefetch next x/R (issued after poll loads -> doesn't delay them)
        if (t + 1 < TT) {
            xv0n = x[((t + 1) * BB + b) * II + lane];
            xv1n = x[((t + 1) * BB + b) * II + lane + 64];
            Rvn  = Rs[(t + 1) * BB + b];
        }

        // ---- poll completion: 4-deep pipelined reload (proven R7/R8) ----
        if (t < TT - 1 && prow >= 0) {
            int guard = 0;
            while (va < 1.0f && ++guard < 2000000) {   // failsafe: never hang
                va = vb; vb = vc; vc = vd;
                vd = __hip_atomic_load(p2, __ATOMIC_RELAXED, __HIP_MEMORY_SCOPE_AGENT);
            }
            so_nxt[prow] = va - 2.0f;
        }
        __syncthreads();                                   // B2: so_nxt sealed
    }

    // ======== final phase (proven structure, unchanged) ========
    // Barrier A among the 8 sibling blocks: everyone's t-loop done, all hs published.
    if (tid == 0) {
        __hip_atomic_fetch_add(&ctr[b * 32], 1u, __ATOMIC_RELAXED, __HIP_MEMORY_SCOPE_AGENT);
        int guard = 0;
        while (__hip_atomic_load(&ctr[b * 32], __ATOMIC_RELAXED, __HIP_MEMORY_SCOPE_AGENT) < 8u) {
            if (++guard > 2000000) break;
            __builtin_amdgcn_s_sleep(1);
        }
    }
    __syncthreads();

    // readout staging: load biased hs, subtract bias
    for (int idx = tid; idx < 16 * HH; idx += 512) {
        int tl = idx / HH, h = idx % HH;
        int t_g = sub * 16 + tl;
        s_hs[idx] = __hip_atomic_load(&hs[(t_g * BB + b) * HH + h],
                                      __ATOMIC_RELAXED, __HIP_MEMORY_SCOPE_AGENT) - 2.0f;
    }
    __syncthreads();
    {
        int t_loc = tid >> 5;          // 0..15
        int o     = tid & 31;
        int t_g   = sub * 16 + t_loc;
        const float* hp = &s_hs[t_loc * HH];
        float acc = bh2o[o];
#pragma unroll 4
        for (int h = 0; h < 257; ++h) {          // mask_o zero for h>256
            float m = (h == 256) ? -1.f : 1.f;   // h==256: sign -1, exist 1 (zc=63)
            acc = fmaf(fmaxf(Wh2o[o * HH + h], 0.f) * m, hp[h], acc);
        }
        float sg = frcp(1.f + fexp2(-acc * L2E));
        out[(t_g * BB + b) * OO + o] = sg;
    }

    // Barrier B: all siblings finished READING biased hs -> safe to rewrite
    __syncthreads();
    if (tid == 0) {
        __hip_atomic_fetch_add(&ctr[b * 32], 1u, __ATOMIC_RELAXED, __HIP_MEMORY_SCOPE_AGENT);
        int guard = 0;
        while (__hip_atomic_load(&ctr[b * 32], __ATOMIC_RELAXED, __HIP_MEMORY_SCOPE_AGENT) < 16u) {
            if (++guard > 2000000) break;
            __builtin_amdgcn_s_sleep(1);
        }
    }
    __syncthreads();

    // rewrite own rows of hs with TRUE values (word-granular agent stores)
    for (int idx = tid; idx < 40 * TT; idx += 512) {
        int row = idx >> 7;            // idx / 128
        int t   = idx & 127;
        __hip_atomic_store(&hs[(t * BB + b) * HH + h0 + row], s_hist[row * HPAD + t],
                           __ATOMIC_RELAXED, __HIP_MEMORY_SCOPE_AGENT);
    }
}

extern "C" void kernel_launch(void* const* d_in, const int* in_sizes, int n_in,
                              void* d_out, int out_size, void* d_ws, size_t ws_size,
                              hipStream_t stream) {
    const float* x     = (const float*)d_in[0];
    const float* Rs    = (const float*)d_in[1];
    const float* Wx2h  = (const float*)d_in[2];
    const float* Wh2h  = (const float*)d_in[3];
    const float* bh2h  = (const float*)d_in[4];
    const float* Wh2o  = (const float*)d_in[5];
    const float* bh2o  = (const float*)d_in[6];
    const float* Wattn = (const float*)d_in[7];
    const float* battn = (const float*)d_in[8];
    const float* cplas = (const float*)d_in[9];
    float* out = (float*)d_out;
    float* hs  = out + TT * BB * OO;
    unsigned* ctr = (unsigned*)d_ws;   // 32 counters, 128B apart

    hipMemsetAsync(d_ws, 0, 32 * 32 * sizeof(unsigned), stream);
    hipLaunchKernelGGL(leaky_rnn_kernel, dim3(256), dim3(512), 0, stream,
                       x, Rs, Wx2h, Wh2h, bh2h, Wh2o, bh2o, Wattn, battn, cplas,
                       out, hs, ctr);
}

// Round 14
// 438.935 us; speedup vs baseline: 2.5726x; 1.0434x over previous
//
#include <hip/hip_runtime.h>

#define TT 128
#define BB 32
#define II 128
#define HH 320
#define OO 32
#define GG 8
#define HPAD 129   // s_hist row pitch (pad: rows are read down-column in final rewrite)

static __device__ __forceinline__ float fexp2(float x) { return __builtin_amdgcn_exp2f(x); }
static __device__ __forceinline__ float frcp(float x)  { return __builtin_amdgcn_rcpf(x); }

// tanh for x >= 0: 1 - 2/(e^{2x}+1), e^{2x} = exp2(x * 2*log2(e))
static __device__ __forceinline__ float tanh_pos(float x) {
    float e = fexp2(x * 2.8853900817779268f);
    return 1.0f - 2.0f * frcp(e + 1.0f);
}

// ---- DPP wave-64 sum reduce (VALU pipe, ~10cy/level) ----
template<int CTRL>
static __device__ __forceinline__ float dpp_add(float v) {
    int t = __builtin_amdgcn_update_dpp(0, __builtin_bit_cast(int, v),
                                        CTRL, 0xf, 0xf, true);
    return v + __builtin_bit_cast(float, t);
}
static __device__ __forceinline__ float bcast63(float v) {
    return __builtin_bit_cast(float,
        __builtin_amdgcn_readlane(__builtin_bit_cast(int, v), 63));
}
static __device__ __forceinline__ float wave_sum(float v) {
    v = dpp_add<0x111>(v);   // row_shr:1
    v = dpp_add<0x112>(v);   // row_shr:2
    v = dpp_add<0x114>(v);   // row_shr:4
    v = dpp_add<0x118>(v);   // row_shr:8
    v = dpp_add<0x142>(v);   // row_bcast:15
    v = dpp_add<0x143>(v);   // row_bcast:31
    return bcast63(v);
}

__global__ __launch_bounds__(512, 2)
void leaky_rnn_kernel(const float* __restrict__ x, const float* __restrict__ Rs,
                      const float* __restrict__ Wx2h, const float* __restrict__ Wh2h,
                      const float* __restrict__ bh2h, const float* __restrict__ Wh2o,
                      const float* __restrict__ bh2o, const float* __restrict__ Wattn,
                      const float* __restrict__ battn, const float* __restrict__ cplas,
                      float* __restrict__ out, float* __restrict__ hs,
                      unsigned* __restrict__ ctr)
{
    const int tid  = threadIdx.x;
    const int bid  = blockIdx.x;
    const int b    = bid >> 3;     // batch  (round-0 proven mapping)
    const int sub  = bid & 7;      // 8 blocks per batch, 40 rows each
    const int w    = tid >> 6;     // wave 0..7
    const int lane = tid & 63;
    const int h0   = sub * 40;

    __shared__ float s_ea[GG * HH];      // masked relu(W_attn)
    __shared__ float s_out[2][HH];       // double-buffered prev-output (by t parity)
    __shared__ float s_logit[GG];
    __shared__ float s_hist[40 * HPAD];  // own 40 rows x 128 t (true values);
                                         // in-loop WRITTEN only (publisher lanes),
                                         // READ only in the final phase after barriers.
    __shared__ float s_hs[16 * HH];      // readout staging

    // ---- one-time init ----
    for (int idx = tid; idx < GG * HH; idx += 512) {
        int h = idx % HH;
        float m = (h < 256) ? 1.f : (h == 256 ? -1.f : 0.f);  // mask_a (zc=63!)
        s_ea[idx] = fmaxf(Wattn[idx], 0.f) * m;
    }
    if (tid < HH) { s_out[0][tid] = 0.f; s_out[1][tid] = 0.f; }  // output0 = relu(0)

    // plastic weights in registers: 5 rows/wave, lane owns cols {lane, lane+64,...}
    float wx[5][2], wh[5][5], st[5], bh[5];
    int hrow[5];
#pragma unroll
    for (int r = 0; r < 5; ++r) {
        int h = h0 + w * 5 + r;
        hrow[r] = h;
        bh[r] = bh2h[h];
        st[r] = 0.f;
#pragma unroll
        for (int c = 0; c < 2; ++c)
            wx[r][c] = fmaxf(Wx2h[h * II + lane + 64 * c], 0.f);   // wx0 = relu(W_x2h)
#pragma unroll
        for (int c = 0; c < 5; ++c) {
            int j = lane + 64 * c;
            float v = fmaxf(Wh2h[h * HH + j], 0.f);
            v = (c == 4) ? -v : v;            // sign_h: j>=256 -> -1
            wh[r][c] = (j == h) ? 0.f : v;    // zero diagonal (1-eye)
        }
    }
    float batt = battn[w];  // wave w handles attn group g = w
    float c0 = fabsf(cplas[0]), c1 = fabsf(cplas[1]), c2 = fabsf(cplas[2]);
    float c3 = fabsf(cplas[3]), c4 = fabsf(cplas[4]), c5 = fabsf(cplas[5]);

    const float AX  = (float)(0.02 / 0.1);   // 0.2
    const float AW  = (float)(0.02 / 0.2);   // 0.1
    const float OMX = 1.f - AX;
    const float OMW = 1.f - AW;
    const float L2E = 1.4426950408889634f;

    __syncthreads();

    // prefetch x (both halves, per-thread regs) and Rs for t=0
    float xv0n = x[b * II + lane];
    float xv1n = x[b * II + lane + 64];
    float Rvn  = Rs[b];

#pragma unroll 1
    for (int t = 0; t < TT; ++t) {
        const float* so_cur = s_out[t & 1];
        float*       so_nxt = s_out[(t + 1) & 1];
        float xv0 = xv0n, xv1 = xv1n;
        float A   = AW * Rvn;

        // ---- attention logits: g = w, reduce over H (DPP, VALU pipe) ----
        float lp = 0.f;
#pragma unroll
        for (int k = 0; k < 5; ++k) {
            int hh2 = lane + 64 * k;
            lp = fmaf(s_ea[w * HH + hh2], so_cur[hh2], lp);
        }
        float lt = wave_sum(lp);
        if (lane == 0) s_logit[w] = lt + batt;
        __syncthreads();                                   // B1: s_logit visible

        // ---- redundant per-thread softmax (no staging barrier) ----
        float lg[8];
#pragma unroll
        for (int g = 0; g < 8; ++g) lg[g] = s_logit[g];
        float mx = lg[0];
#pragma unroll
        for (int g = 1; g < 8; ++g) mx = fmaxf(mx, lg[g]);
        float se = 0.f, eg[8];
#pragma unroll
        for (int g = 0; g < 8; ++g) { eg[g] = fexp2((lg[g] - mx) * L2E); se += eg[g]; }
        float rinv = frcp(se);
        float xmc0 = xv0 * eg[lane >> 4] * 8.f * rinv;
        float xmc1 = xv1 * eg[(lane >> 4) + 4] * 8.f * rinv;

        float oc[5];
#pragma unroll
        for (int c = 0; c < 5; ++c) oc[c] = so_cur[lane + 64 * c];

        // ---- 5 row-dot partials, 5-way ILP DPP reduce ----
        float p[5];
#pragma unroll
        for (int r = 0; r < 5; ++r) {
            int h = hrow[r];
            float pp = fmaxf(wx[r][0], 0.f) * xmc0;
            pp = fmaf(fmaxf(wx[r][1], 0.f), xmc1, pp);
#pragma unroll
            for (int c = 0; c < 5; ++c) {
                float wv = fmaxf(wh[r][c], 0.f);
                float so = (c == 4) ? -oc[4] : oc[c];        // sign_h fold
                float term = wv * so;
                term = ((lane + 64 * c) == h) ? 0.f : term;  // exclude diagonal
                pp += term;
            }
            p[r] = pp;
        }
#define DPP_L5(CTRL) { \
        p[0]=dpp_add<CTRL>(p[0]); p[1]=dpp_add<CTRL>(p[1]); \
        p[2]=dpp_add<CTRL>(p[2]); p[3]=dpp_add<CTRL>(p[3]); \
        p[4]=dpp_add<CTRL>(p[4]); }
        DPP_L5(0x111) DPP_L5(0x112) DPP_L5(0x114)
        DPP_L5(0x118) DPP_L5(0x142) DPP_L5(0x143)
#undef DPP_L5

        float no[5];
#pragma unroll
        for (int r = 0; r < 5; ++r) {
            float total = bcast63(p[r]) + bh[r];
            st[r] = fmaf(st[r], OMX, total * AX);
            no[r] = tanh_pos(fmaxf(st[r], 0.f));
        }

        // ---- batched publish: lanes 0..4 store 5 consecutive h (one line).
        //      Biased (+2): poison 0xAA.. and memset-0 are < 1.
        //      Publisher ALSO writes its true value into so_nxt (LDS):
        //      race-free own-row fast path -- B2 below orders this write
        //      against all next-step readers. ----
        {
            float pub = no[0];
            pub = (lane == 1) ? no[1] : pub;
            pub = (lane == 2) ? no[2] : pub;
            pub = (lane == 3) ? no[3] : pub;
            pub = (lane == 4) ? no[4] : pub;
            if (lane < 5) {
                __hip_atomic_store(&hs[(t * BB + b) * HH + h0 + w * 5 + lane], pub + 2.0f,
                                   __ATOMIC_RELAXED, __HIP_MEMORY_SCOPE_AGENT);
                s_hist[(w * 5 + lane) * HPAD + t] = pub;   // true value for final rewrite
                so_nxt[h0 + w * 5 + lane] = pub;           // own-row fast path (B2-ordered)
            }
        }

        // ---- plastic weight update (regs only; overlaps store propagation) ----
        if (t < TT - 1) {
            float Ac0 = A * c0, Ac1 = A * c1, Ac2 = A * c2;
            float Ac3 = A * c3, Ac4 = A * c4, Ac5 = A * c5;
#pragma unroll
            for (int r = 0; r < 5; ++r) {
                float u  = fmaf(Ac2, no[r], Ac0);
                float v  = Ac1 * no[r];
                float pp = fmaf(Ac5, no[r], Ac3);
                float qq = Ac4 * no[r];
                wx[r][0] = fmaf(wx[r][0], OMW, fmaf(u, xmc0, v));
                wx[r][1] = fmaf(wx[r][1], OMW, fmaf(u, xmc1, v));
#pragma unroll
                for (int c = 0; c < 5; ++c)
                    wh[r][c] = fmaf(wh[r][c], OMW, fmaf(pp, oc[c], qq));
            }
        }

        // prefetch next x/R while publish stores are in flight
        if (t + 1 < TT) {
            xv0n = x[((t + 1) * BB + b) * II + lane];
            xv1n = x[((t + 1) * BB + b) * II + lane + 64];
            Rvn  = Rs[(t + 1) * BB + b];
        }

        // ---- gather the 280 REMOTE rows into the other buffer (own 40 rows
        //      were written to so_nxt by the publishers above; B2 orders).
        //      4-deep pipelined poll (proven R7/R8). ----
        if (t < TT - 1 && tid < HH && !(tid >= h0 && tid < h0 + 40)) {
            const float* p2 = &hs[(t * BB + b) * HH + tid];
            float va = __hip_atomic_load(p2, __ATOMIC_RELAXED, __HIP_MEMORY_SCOPE_AGENT);
            float vb = __hip_atomic_load(p2, __ATOMIC_RELAXED, __HIP_MEMORY_SCOPE_AGENT);
            float vc = __hip_atomic_load(p2, __ATOMIC_RELAXED, __HIP_MEMORY_SCOPE_AGENT);
            float vd = __hip_atomic_load(p2, __ATOMIC_RELAXED, __HIP_MEMORY_SCOPE_AGENT);
            int guard = 0;
            while (va < 1.0f && ++guard < 2000000) {   // failsafe: never hang
                va = vb; vb = vc; vc = vd;
                vd = __hip_atomic_load(p2, __ATOMIC_RELAXED, __HIP_MEMORY_SCOPE_AGENT);
            }
            so_nxt[tid] = va - 2.0f;
        }
        __syncthreads();                                   // B2: so_nxt sealed
    }

    // ======== final phase (proven structure) ========
    // Barrier A among the 8 sibling blocks: everyone's t-loop done, all hs published.
    if (tid == 0) {
        __hip_atomic_fetch_add(&ctr[b * 32], 1u, __ATOMIC_RELAXED, __HIP_MEMORY_SCOPE_AGENT);
        int guard = 0;
        while (__hip_atomic_load(&ctr[b * 32], __ATOMIC_RELAXED, __HIP_MEMORY_SCOPE_AGENT) < 8u) {
            if (++guard > 2000000) break;
            __builtin_amdgcn_s_sleep(1);
        }
    }
    __syncthreads();

    // readout staging: load biased hs, subtract bias
    for (int idx = tid; idx < 16 * HH; idx += 512) {
        int tl = idx / HH, h = idx % HH;
        int t_g = sub * 16 + tl;
        s_hs[idx] = __hip_atomic_load(&hs[(t_g * BB + b) * HH + h],
                                      __ATOMIC_RELAXED, __HIP_MEMORY_SCOPE_AGENT) - 2.0f;
    }
    __syncthreads();
    {
        int t_loc = tid >> 5;          // 0..15
        int o     = tid & 31;
        int t_g   = sub * 16 + t_loc;
        const float* hp = &s_hs[t_loc * HH];
        float acc = bh2o[o];
#pragma unroll 4
        for (int h = 0; h < 257; ++h) {          // mask_o zero for h>256
            float m = (h == 256) ? -1.f : 1.f;   // h==256: sign -1, exist 1 (zc=63)
            acc = fmaf(fmaxf(Wh2o[o * HH + h], 0.f) * m, hp[h], acc);
        }
        float sg = frcp(1.f + fexp2(-acc * L2E));
        out[(t_g * BB + b) * OO + o] = sg;
    }

    // Barrier B: all siblings finished READING biased hs -> safe to rewrite
    __syncthreads();
    if (tid == 0) {
        __hip_atomic_fetch_add(&ctr[b * 32], 1u, __ATOMIC_RELAXED, __HIP_MEMORY_SCOPE_AGENT);
        int guard = 0;
        while (__hip_atomic_load(&ctr[b * 32], __ATOMIC_RELAXED, __HIP_MEMORY_SCOPE_AGENT) < 16u) {
            if (++guard > 2000000) break;
            __builtin_amdgcn_s_sleep(1);
        }
    }
    __syncthreads();

    // rewrite own rows of hs with TRUE values (word-granular agent stores)
    for (int idx = tid; idx < 40 * TT; idx += 512) {
        int row = idx >> 7;            // idx / 128
        int t   = idx & 127;
        __hip_atomic_store(&hs[(t * BB + b) * HH + h0 + row], s_hist[row * HPAD + t],
                           __ATOMIC_RELAXED, __HIP_MEMORY_SCOPE_AGENT);
    }
}

extern "C" void kernel_launch(void* const* d_in, const int* in_sizes, int n_in,
                              void* d_out, int out_size, void* d_ws, size_t ws_size,
                              hipStream_t stream) {
    const float* x     = (const float*)d_in[0];
    const float* Rs    = (const float*)d_in[1];
    const float* Wx2h  = (const float*)d_in[2];
    const float* Wh2h  = (const float*)d_in[3];
    const float* bh2h  = (const float*)d_in[4];
    const float* Wh2o  = (const float*)d_in[5];
    const float* bh2o  = (const float*)d_in[6];
    const float* Wattn = (const float*)d_in[7];
    const float* battn = (const float*)d_in[8];
    const float* cplas = (const float*)d_in[9];
    float* out = (float*)d_out;
    float* hs  = out + TT * BB * OO;
    unsigned* ctr = (unsigned*)d_ws;   // 32 counters, 128B apart

    hipMemsetAsync(d_ws, 0, 32 * 32 * sizeof(unsigned), stream);
    hipLaunchKernelGGL(leaky_rnn_kernel, dim3(256), dim3(512), 0, stream,
                       x, Rs, Wx2h, Wh2h, bh2h, Wh2o, bh2o, Wattn, battn, cplas,
                       out, hs, ctr);
}